// Round 6
// baseline (229.101 us; speedup 1.0000x reference)
//
#include <hip/hip_runtime.h>
#include <hip/hip_bf16.h>
#include <math.h>

#define B_  2
#define L_  2048
#define D_  2048
#define H_  16
#define HD_ 128
#define EPS_ 1e-5f

typedef __attribute__((ext_vector_type(8)))  short short8;
typedef __attribute__((ext_vector_type(4)))  float f32x4;
typedef __attribute__((ext_vector_type(16))) float f32x16;

static __device__ inline unsigned short bfb(float x) {
    __hip_bfloat16 h = __float2bfloat16(x);
    unsigned short s;
    __builtin_memcpy(&s, &h, 2);
    return s;
}
static __device__ inline unsigned pk2(float a, float b) {
    return (unsigned)bfb(a) | ((unsigned)bfb(b) << 16);
}

// direct-to-LDS 16B copy: LDS dest = wave-uniform base + lane*16
static __device__ __forceinline__ void gld_lds16(const void* g, void* l) {
    __builtin_amdgcn_global_load_lds(
        (const __attribute__((address_space(1))) unsigned int*)g,
        (__attribute__((address_space(3))) unsigned int*)l,
        16, 0, 0);
}

// ---------------------------------------------------------------------------
// fused cast f32 -> bf16 for x, Wq, Wk, Wv (dsts contiguous in ws)
// ---------------------------------------------------------------------------
#define XN4 2097152              // 8388608/4
#define WN4 1048576              // 4194304/4
#define TOT4 (XN4 + 3 * WN4)     // 5242880

__global__ __launch_bounds__(256) void cast4_kernel(
    const float* __restrict__ x,  const float* __restrict__ Wq,
    const float* __restrict__ Wk, const float* __restrict__ Wv,
    __hip_bfloat16* __restrict__ dst)
{
    int i = blockIdx.x * 256 + threadIdx.x;
    const int st = gridDim.x * 256;
    for (; i < TOT4; i += st) {
        const float* s;
        int off;
        if (i < XN4)                { s = x;  off = i; }
        else if (i < XN4 + WN4)     { s = Wq; off = i - XN4; }
        else if (i < XN4 + 2 * WN4) { s = Wk; off = i - XN4 - WN4; }
        else                        { s = Wv; off = i - XN4 - 2 * WN4; }
        float4 v = ((const float4*)s)[off];
        uint2 r;
        r.x = pk2(v.x, v.y);
        r.y = pk2(v.z, v.w);
        ((uint2*)dst)[i] = r;
    }
}

// ---------------------------------------------------------------------------
// Fused projection GEMM (bf16 MFMA), counted-vmcnt deep pipeline.
// Out[m,n] = sum_k X[m,k] * Wcat[n,k],  M=4096, N=6144 (Wq|Wk|Wv), K=2048.
// 256x128 tile, 8 waves (4Mx2N, wave tile 64x64), BK=32, 4-deep LDS buffer
// rotation (96 KB).  Tile t computes while t+3 stages; s_waitcnt vmcnt(6)
// steady state (never 0 in main loop); raw s_barrier (no vmcnt drain).
// LDS layout (A and B identical): superrow sr = row>>1 (128 B), half = row&1
// (64 B), 16B slot s16 stores source k-slot (s16 ^ (sr&3))  -> all fragment
// reads and stages are 2-way-max bank aliasing (free).
// n -> z = n>>11 (0:Q, 1:K, 2:V);  Q,K written [b,h,l,hd]; V written [b,h,hd,l].
// ---------------------------------------------------------------------------
#define NT_ 64   // K / 32

__global__ __launch_bounds__(512, 2) void proj_fused(
    const __hip_bfloat16* __restrict__ X,
    const __hip_bfloat16* __restrict__ Wc,
    __hip_bfloat16* __restrict__ Qo, __hip_bfloat16* __restrict__ Ko,
    __hip_bfloat16* __restrict__ VT)
{
    __shared__ __align__(16) char lds[98304];   // 4 bufs x (A 16K + B 8K)

    const int t   = threadIdx.x;
    const int w   = t >> 6, l = t & 63;
    const int li  = l & 15, hi4 = l >> 4;
    const int wr  = w >> 1, wcn = w & 1;

    // XCD-aware swizzle: 768 blocks, 96 per XCD (bijective since 768%8==0)
    const int wg = ((blockIdx.x & 7) * 96) + (blockIdx.x >> 3);
    const int m0 = (wg & 15) * 256;
    const int n0 = (wg >> 4) * 128;

    // staging source geometry (same for A-units and B): unit = 128 rows.
    // dest linear 1KB/wave: superrow w*8+(l>>3), half (l&7)>>2, slot l&3.
    const int srow   = 16 * w + 2 * (l >> 3) + ((l & 7) >> 2);
    const int kslot8 = ((l & 3) ^ ((l >> 3) & 3)) * 8;

    // fragment-read offset (A and B symmetric): row = wX*64 + f*16 + li
    const int fro  = (li >> 1) * 128 + (li & 1) * 64 + ((hi4 ^ ((li >> 1) & 3)) << 4);
    const int aoff = wr  * 4096 + fro;
    const int boff = wcn * 4096 + fro;

    auto STAGE = [&](int tt) {
        char* Ab = lds + (tt & 3) * 24576;
        const size_t kc = (size_t)(tt * 32) + kslot8;
        gld_lds16(X  + (size_t)(m0 + srow) * D_ + kc,       Ab + w * 1024);
        gld_lds16(X  + (size_t)(m0 + 128 + srow) * D_ + kc, Ab + 8192 + w * 1024);
        gld_lds16(Wc + (size_t)(n0 + srow) * D_ + kc,       Ab + 16384 + w * 1024);
    };

    f32x4 acc[4][4];
    #pragma unroll
    for (int i = 0; i < 4; ++i)
        #pragma unroll
        for (int j = 0; j < 4; ++j)
            #pragma unroll
            for (int r = 0; r < 4; ++r) acc[i][j][r] = 0.f;

    STAGE(0); STAGE(1); STAGE(2);
    asm volatile("s_waitcnt vmcnt(6)" ::: "memory");   // tile 0 landed
    __builtin_amdgcn_s_barrier();

    for (int tq = 0; tq < NT_ / 4; ++tq) {
        #pragma unroll
        for (int j = 0; j < 4; ++j) {
            const int tt = tq * 4 + j;
            const char* Ab = lds + j * 24576;
            const char* Bb = Ab + 16384;

            short8 af[4], bfr[4];
            #pragma unroll
            for (int mi = 0; mi < 4; ++mi)
                af[mi] = *(const short8*)(Ab + aoff + mi * 1024);
            #pragma unroll
            for (int ni = 0; ni < 4; ++ni)
                bfr[ni] = *(const short8*)(Bb + boff + ni * 1024);

            if (tt <= NT_ - 4) STAGE(tt + 3);

            if (tt <= NT_ - 4)      asm volatile("s_waitcnt vmcnt(6)" ::: "memory");
            else if (tt == NT_ - 3) asm volatile("s_waitcnt vmcnt(3)" ::: "memory");
            else if (tt == NT_ - 2) asm volatile("s_waitcnt vmcnt(0)" ::: "memory");

            __builtin_amdgcn_sched_barrier(0);
            __builtin_amdgcn_s_barrier();
            __builtin_amdgcn_sched_barrier(0);

            __builtin_amdgcn_s_setprio(1);
            #pragma unroll
            for (int mi = 0; mi < 4; ++mi)
                #pragma unroll
                for (int ni = 0; ni < 4; ++ni)
                    acc[mi][ni] = __builtin_amdgcn_mfma_f32_16x16x32_bf16(
                        af[mi], bfr[ni], acc[mi][ni], 0, 0, 0);
            __builtin_amdgcn_s_setprio(0);

            __builtin_amdgcn_sched_barrier(0);
            __builtin_amdgcn_s_barrier();
            __builtin_amdgcn_sched_barrier(0);
        }
    }

    // epilogue: C[r]: row = hi4*4 + r, col = li  (within each 16x16 frag)
    const int zsel = n0 >> 11;
    const int np   = n0 & (D_ - 1);
    if (zsel == 2) {
        // V transposed: VT[b][np + col][l]; 4 consecutive l per lane -> 8B store
        #pragma unroll
        for (int mi = 0; mi < 4; ++mi) {
            #pragma unroll
            for (int ni = 0; ni < 4; ++ni) {
                const int n     = np + wcn * 64 + ni * 16 + li;
                const int mbase = m0 + wr * 64 + mi * 16 + hi4 * 4;
                const int b = mbase >> 11, ml = mbase & (L_ - 1);
                uint2 w2;
                w2.x = pk2(acc[mi][ni][0], acc[mi][ni][1]);
                w2.y = pk2(acc[mi][ni][2], acc[mi][ni][3]);
                *(uint2*)&VT[((size_t)b * D_ + n) * L_ + ml] = w2;
            }
        }
    } else {
        __hip_bfloat16* O = zsel ? Ko : Qo;
        #pragma unroll
        for (int mi = 0; mi < 4; ++mi) {
            #pragma unroll
            for (int ni = 0; ni < 4; ++ni) {
                const int n  = np + wcn * 64 + ni * 16 + li;
                const int h  = n >> 7, hd = n & (HD_ - 1);
                #pragma unroll
                for (int r = 0; r < 4; ++r) {
                    const int m = m0 + wr * 64 + mi * 16 + hi4 * 4 + r;
                    const int b = m >> 11, ml = m & (L_ - 1);
                    O[((size_t)(b * H_ + h) * L_ + ml) * HD_ + hd] =
                        __float2bfloat16(acc[mi][ni][r]);
                }
            }
        }
    }
}

// ---------------------------------------------------------------------------
// Retention (bf16 MFMA): out[b,h,i,:] = sum_{j<=i} (q_i.k_j)*scale*g^(i-j) v_j
// (unchanged from the round-5 passing version)
// ---------------------------------------------------------------------------
__global__ __launch_bounds__(256) void retn_kernel(
    const __hip_bfloat16* __restrict__ Qb, const __hip_bfloat16* __restrict__ Kb,
    const __hip_bfloat16* __restrict__ VT, const float* __restrict__ gl,
    float* __restrict__ out)
{
    const int bid = blockIdx.x;
    const int mm  = bid >> 5;
    const int m   = (mm < 8) ? (15 - mm) : (mm - 8);   // pairs sum to 15 per CU
    const int bh  = bid & 31;
    const int b   = bh >> 4, h = bh & (H_ - 1);
    const int t   = threadIdx.x;
    const int w   = t >> 6, l = t & 63;
    const int li  = l & 31, hi = l >> 5;

    const float gamma = 1.f / (1.f + __expf(-gl[h]));
    const float lg2   = __log2f(gamma);
    const float scale = 0.08838834764831845f;   // 128^-0.5

    __shared__ __align__(16) char Klds[32768];   // [128 j][128 e] swizzled
    __shared__ __align__(16) char Vlds[32768];   // [128 d][128 j] swizzled

    const size_t base = (size_t)bh * (L_ * HD_);
    const __hip_bfloat16* VTg = VT + (size_t)bh * (HD_ * L_);
    const int i0 = m * 128 + w * 32;            // this wave's first Q row

    // hoist Q fragments: B-operand for S^T (col = li, k slices)
    short8 qf[8];
    {
        const __hip_bfloat16* qrow = Qb + base + (size_t)(i0 + li) * HD_;
        #pragma unroll
        for (int s = 0; s < 8; ++s)
            qf[s] = *(const short8*)(qrow + s * 16 + hi * 8);
    }

    // per-lane decay factors gamma^(i_loc - j_loc) for the 16 C-regs
    float df[16];
    #pragma unroll
    for (int r = 0; r < 16; ++r) {
        const int jl = (r & 3) + 8 * (r >> 2) + 4 * hi;
        df[r] = exp2f(lg2 * (float)(li - jl));
    }

    f32x16 acc[4];
    #pragma unroll
    for (int c = 0; c < 4; ++c)
        #pragma unroll
        for (int r = 0; r < 16; ++r) acc[c][r] = 0.f;

    const int srow4 = l >> 4;        // 0..3 row-within-chunk
    const int sslot = l & 15;        // 16B slot

    for (int gj = 0; gj <= m * 128; gj += 128) {
        __syncthreads();             // prev group fully consumed
        #pragma unroll
        for (int cc = 0; cc < 8; ++cc) {
            const int c  = w * 8 + cc;            // chunk 0..31 (4 rows each)
            const int r  = c * 4 + srow4;         // row 0..127
            const int sc = ((sslot ^ (r & 15)) * 8);
            gld_lds16(Kb + base + (size_t)(gj + r) * HD_ + sc, Klds + c * 1024);
            gld_lds16(VTg + (size_t)r * L_ + gj + sc,          Vlds + c * 1024);
        }
        __syncthreads();             // (compiler drains vmcnt before barrier)

        const int tmax = ((i0 - gj) >> 5) < 3 ? ((i0 - gj) >> 5) : 3;
        for (int jt = 0; jt <= tmax; ++jt) {
            const int j0 = gj + jt * 32;

            // QK^T: S^T[j,i], j = C-rows, i = C-col (= li)
            f32x16 c;
            #pragma unroll
            for (int r = 0; r < 16; ++r) c[r] = 0.f;
            #pragma unroll
            for (int s = 0; s < 8; ++s) {
                short8 kf = *(const short8*)(Klds + (jt * 32 + li) * 256 +
                                             (((s * 2 + hi) ^ (li & 15)) << 4));
                c = __builtin_amdgcn_mfma_f32_32x32x16_bf16(kf, qf[s], c, 0, 0, 0);
            }

            // decay (+ diagonal mask)
            float p[16];
            const float bt = exp2f(lg2 * (float)(i0 - j0)) * scale;
            if (j0 == i0) {
                #pragma unroll
                for (int r = 0; r < 16; ++r) {
                    const int jl = (r & 3) + 8 * (r >> 2) + 4 * hi;
                    p[r] = (jl <= li) ? c[r] * (df[r] * bt) : 0.f;
                }
            } else {
                #pragma unroll
                for (int r = 0; r < 16; ++r) p[r] = c[r] * (df[r] * bt);
            }

            // two k-slices (j 0..15 from regs 0..7, j 16..31 from regs 8..15)
            #pragma unroll
            for (int sl = 0; sl < 2; ++sl) {
                const int o = sl * 8;
                unsigned pk01 = pk2(p[o + 0], p[o + 1]);
                unsigned pk23 = pk2(p[o + 2], p[o + 3]);
                unsigned pk45 = pk2(p[o + 4], p[o + 5]);
                unsigned pk67 = pk2(p[o + 6], p[o + 7]);
                unsigned x01 = (unsigned)__shfl_xor((int)pk01, 32);
                unsigned x23 = (unsigned)__shfl_xor((int)pk23, 32);
                unsigned x45 = (unsigned)__shfl_xor((int)pk45, 32);
                unsigned x67 = (unsigned)__shfl_xor((int)pk67, 32);
                union { short8 v; unsigned u[4]; } pf;
                pf.u[0] = hi ? x45 : pk01;
                pf.u[1] = hi ? x67 : pk23;
                pf.u[2] = hi ? pk45 : x01;
                pf.u[3] = hi ? pk67 : x23;
                #pragma unroll
                for (int cch = 0; cch < 4; ++cch) {
                    short8 vf = *(const short8*)(Vlds + (cch * 32 + li) * 256 +
                                 (((jt * 4 + sl * 2 + hi) ^ (li & 15)) << 4));
                    acc[cch] = __builtin_amdgcn_mfma_f32_32x32x16_bf16(
                        pf.v, vf, acc[cch], 0, 0, 0);
                }
            }
        }
    }

    // epilogue: acc[cch] C-layout: col d = cch*32+li, row = (r&3)+8*(r>>2)+4*hi
    #pragma unroll
    for (int cch = 0; cch < 4; ++cch) {
        #pragma unroll
        for (int r = 0; r < 16; ++r) {
            const int row = (r & 3) + 8 * (r >> 2) + 4 * hi;
            out[(size_t)(b * L_ + i0 + row) * D_ + h * HD_ + cch * 32 + li] =
                acc[cch][r];
        }
    }
}

// ---------------------------------------------------------------------------
// GroupNorm, two-pass full-chip: stats (512 blocks) + apply (2048 blocks)
// ---------------------------------------------------------------------------
__global__ __launch_bounds__(256) void gn_stats(
    const float* __restrict__ out, float2* __restrict__ part)
{
    const int bh = blockIdx.x, sl = blockIdx.y;    // (32, 16)
    const int b = bh >> 4, h = bh & (H_ - 1);
    const int t = threadIdx.x;

    float s = 0.f, sq = 0.f;
    #pragma unroll 4
    for (int it = 0; it < 16; ++it) {
        const int n  = it * 256 + t;               // float4 index in slice (4096)
        const int ll = n >> 5, d4 = n & 31;        // 32 float4 per row
        float4 v = *(const float4*)&out[(size_t)(b * L_ + sl * 128 + ll) * D_ + h * HD_ + d4 * 4];
        s  += v.x + v.y + v.z + v.w;
        sq += v.x * v.x + v.y * v.y + v.z * v.z + v.w * v.w;
    }
    #pragma unroll
    for (int off = 32; off > 0; off >>= 1) {
        s  += __shfl_down(s, off);
        sq += __shfl_down(sq, off);
    }
    __shared__ float rs[4], rq[4];
    const int wv = t >> 6, lane = t & 63;
    if (lane == 0) { rs[wv] = s; rq[wv] = sq; }
    __syncthreads();
    if (t == 0)
        part[bh * 16 + sl] = make_float2(rs[0] + rs[1] + rs[2] + rs[3],
                                         rq[0] + rq[1] + rq[2] + rq[3]);
}

__global__ __launch_bounds__(256) void gn_apply(
    float* __restrict__ out, const float2* __restrict__ part,
    const float* __restrict__ gw, const float* __restrict__ gb)
{
    const int bh = blockIdx.x, sl = blockIdx.y;    // (32, 64): 32-row slices
    const int b = bh >> 4, h = bh & (H_ - 1);
    const int t = threadIdx.x;

    float S = 0.f, SQ = 0.f;
    #pragma unroll
    for (int i = 0; i < 16; ++i) {
        float2 p = part[bh * 16 + i];
        S += p.x; SQ += p.y;
    }
    const float inv  = 1.f / (float)(L_ * HD_);
    const float mean = S * inv;
    float var = SQ * inv - mean * mean;
    if (var < 0.f) var = 0.f;
    const float rstd = rsqrtf(var + EPS_);

    #pragma unroll
    for (int it = 0; it < 4; ++it) {
        const int n  = it * 256 + t;               // float4 index in slice (1024)
        const int ll = n >> 5, d4 = n & 31;
        const size_t idx = (size_t)(b * L_ + sl * 32 + ll) * D_ + h * HD_ + d4 * 4;
        float4 v = *(const float4*)&out[idx];
        const float4 w4 = *(const float4*)&gw[h * HD_ + d4 * 4];
        const float4 b4 = *(const float4*)&gb[h * HD_ + d4 * 4];
        v.x = (v.x - mean) * rstd * w4.x + b4.x;
        v.y = (v.y - mean) * rstd * w4.y + b4.y;
        v.z = (v.z - mean) * rstd * w4.z + b4.z;
        v.w = (v.w - mean) * rstd * w4.w + b4.w;
        *(float4*)&out[idx] = v;
    }
}

// ---------------------------------------------------------------------------
extern "C" void kernel_launch(void* const* d_in, const int* in_sizes, int n_in,
                              void* d_out, int out_size, void* d_ws, size_t ws_size,
                              hipStream_t stream) {
    const float* x  = (const float*)d_in[0];
    const float* Wq = (const float*)d_in[1];
    const float* Wk = (const float*)d_in[2];
    const float* Wv = (const float*)d_in[3];
    const float* gl = (const float*)d_in[4];
    const float* gw = (const float*)d_in[5];
    const float* gb = (const float*)d_in[6];
    float* out = (float*)d_out;

    __hip_bfloat16* ws = (__hip_bfloat16*)d_ws;
    __hip_bfloat16* xb  = ws;                    // 8,388,608
    __hip_bfloat16* Wqb = xb  + 8388608;         // 4,194,304 each (contiguous cat)
    __hip_bfloat16* Wkb = Wqb + 4194304;
    __hip_bfloat16* Wvb = Wkb + 4194304;
    __hip_bfloat16* Qbf = Wvb + 4194304;         // 8,388,608 each
    __hip_bfloat16* Kbf = Qbf + 8388608;
    __hip_bfloat16* VTb = Kbf + 8388608;         // V transposed [b,h,d,l]
    float2* part = (float2*)(VTb + 8388608);     // 512 float2

    cast4_kernel<<<2048, 256, 0, stream>>>(x, Wq, Wk, Wv, xb);

    proj_fused<<<dim3(768), 512, 0, stream>>>(xb, Wqb, Qbf, Kbf, VTb);

    retn_kernel<<<dim3(512), 256, 0, stream>>>(Qbf, Kbf, VTb, gl, out);

    gn_stats<<<dim3(32, 16), 256, 0, stream>>>(out, part);
    gn_apply<<<dim3(32, 64), 256, 0, stream>>>(out, part, gw, gb);
}